// Round 1
// 55.705 us; speedup vs baseline: 1.0554x; 1.0554x over previous
//
#include <hip/hip_runtime.h>

// ConstrainedAttentionModel: B=8, T=2048, V=8192, K=3.
// scores[b,t] = sum_{i,j, t>=j} params[i][j] * [x[b,t-j] == x[b,T-1-i]]
// scores[b,T-1] = -1e9 ; attn = softmax_t(scores) ; out[b,v] = sum_{t:x[b,t]==v} attn[b,t]
//
// R2: latency-path rewrite. Previous version: 8 blocks, 3 barriers, 40 KB LDS
// (8-iter zero + 8-iter store), x staged through LDS. Residual over the fixed
// 40 us harness poison-fill was ~19 us. This version:
//   - 64 blocks (8 batches x 8 exclusive V-chunks of 1024): each block
//     redundantly computes all T scores (trivial) but owns a 4 KB chunk ->
//     1-iter LDS zero, 1-iter chunk store, no cross-block comms.
//   - no x LDS staging: per-thread contiguous 10-token window loaded as
//     int2+int4+int4 (32 B/lane, coalesced; rows L1/L2-shared across the 8
//     chunk-blocks). Query tokens are wave-uniform scalar loads.
//   - 2 barriers total (zero-visibility folded into the reduction barrier).

constexpr int T = 2048;
constexpr int V = 8192;
constexpr int BLOCK = 256;
constexpr int PER = T / BLOCK;        // 8 positions per thread (contiguous)
constexpr int NWAVE = BLOCK / 64;     // 4 waves
constexpr int NCHUNK = 8;             // V-chunks per batch
constexpr int CHUNK = V / NCHUNK;     // 1024 floats = 4 KB

__global__ __launch_bounds__(BLOCK)
void ca_kernel(const int* __restrict__ x, const float* __restrict__ params,
               float* __restrict__ out) {
    const int b   = blockIdx.x >> 3;       // batch
    const int c   = blockIdx.x & (NCHUNK - 1);  // vocab chunk
    const int tid = threadIdx.x;

    __shared__ float s_acc[CHUNK];         // 4 KB chunk accumulator
    __shared__ float s_red[NWAVE];

    // zero the chunk: exactly one float4 per thread
    reinterpret_cast<float4*>(s_acc)[tid] = make_float4(0.f, 0.f, 0.f, 0.f);

    const int* xb = x + b * T;

    // wave-uniform query tokens (compiler scalarizes these)
    const int q0 = xb[T - 1], q1 = xb[T - 2], q2 = xb[T - 3];

    // params[i][j]: i = query index (x[T-1-i]), j = window offset (x[t-j])
    const float p00 = params[0], p01 = params[1], p02 = params[2];
    const float p10 = params[3], p11 = params[4], p12 = params[5];
    const float p20 = params[6], p21 = params[7], p22 = params[8];

    // per-thread contiguous window x[t0-2 .. t0+7]; sentinel -1 never matches
    const int t0 = tid * PER;
    int tok[PER];
    int m2, m1;
    {
        const int4 a = *reinterpret_cast<const int4*>(xb + t0);       // 16B-aligned
        const int4 d = *reinterpret_cast<const int4*>(xb + t0 + 4);
        tok[0] = a.x; tok[1] = a.y; tok[2] = a.z; tok[3] = a.w;
        tok[4] = d.x; tok[5] = d.y; tok[6] = d.z; tok[7] = d.w;
        if (tid > 0) {
            const int2 p = *reinterpret_cast<const int2*>(xb + t0 - 2); // 8B-aligned
            m2 = p.x; m1 = p.y;
        } else {
            m2 = -1; m1 = -1;   // t<j terms contribute 0 (zero-padding in ref)
        }
    }

    // --- scores + exp (no max-shift: |s| <= 9*max|param| << 80; mask -> exp=0) ---
    float e[PER];
    float lsum = 0.f;
    #pragma unroll
    for (int k = 0; k < PER; ++k) {
        const int tj0 = tok[k];                                   // j = 0
        const int tj1 = (k >= 1) ? tok[k - 1] : m1;               // j = 1
        const int tj2 = (k >= 2) ? tok[k - 2] : (k == 1 ? m1 : m2); // j = 2
        float s = 0.f;
        if (tj0 == q0) s += p00;
        if (tj0 == q1) s += p10;
        if (tj0 == q2) s += p20;
        if (tj1 == q0) s += p01;
        if (tj1 == q1) s += p11;
        if (tj1 == q2) s += p21;
        if (tj2 == q0) s += p02;
        if (tj2 == q1) s += p12;
        if (tj2 == q2) s += p22;
        if (t0 + k == T - 1) s = -1.0e9f;  // masked -> expf underflows to 0
        e[k] = expf(s);
        lsum += e[k];
    }

    // --- block sum (one barrier covers both s_red and the s_acc zeroing) ---
    #pragma unroll
    for (int off = 32; off >= 1; off >>= 1)
        lsum += __shfl_down(lsum, off, 64);
    const int wave = tid >> 6, lane = tid & 63;
    if (lane == 0) s_red[wave] = lsum;
    __syncthreads();                                     // barrier 1
    float S = 0.f;
    #pragma unroll
    for (int w = 0; w < NWAVE; ++w) S += s_red[w];
    const float inv = 1.f / S;

    // --- scatter attn for tokens in this block's chunk (ds_add_f32) ---
    const int vbase = c * CHUNK;
    #pragma unroll
    for (int k = 0; k < PER; ++k) {
        const int v = tok[k] - vbase;
        if ((unsigned)v < (unsigned)CHUNK)
            atomicAdd(&s_acc[v], e[k] * inv);
    }
    __syncthreads();                                     // barrier 2

    // --- coalesced chunk store: one float4 per thread ---
    reinterpret_cast<float4*>(out + b * V + vbase)[tid] =
        reinterpret_cast<const float4*>(s_acc)[tid];
}

extern "C" void kernel_launch(void* const* d_in, const int* in_sizes, int n_in,
                              void* d_out, int out_size, void* d_ws, size_t ws_size,
                              hipStream_t stream) {
    const int* x = (const int*)d_in[0];          // (B, T) int32
    const float* params = (const float*)d_in[1]; // (3, 3) fp32
    float* out = (float*)d_out;                  // (B, V) fp32
    const int B = in_sizes[0] / T;               // 8
    ca_kernel<<<B * NCHUNK, BLOCK, 0, stream>>>(x, params, out);
}

// Round 2
// 55.405 us; speedup vs baseline: 1.0611x; 1.0054x over previous
//
#include <hip/hip_runtime.h>

// ConstrainedAttentionModel: B=8, T=2048, V=8192, K=3.
// scores[b,t] = sum_{i,j, t>=j} params[i][j] * [x[b,t-j] == x[b,T-1-i]]
// scores[b,T-1] = -1e9 ; attn = softmax_t(scores) ; out[b,v] = sum_{t:x[b,t]==v} attn[b,t]
//
// R3: critical-path micro-opts on the R2 structure (64 blocks = 8 batches x 8
// exclusive 4 KB V-chunks, 2 barriers):
//   - __expf (v_exp_f32) instead of libm expf: |s| <= 0.5, ~1-ulp error is
//     ~1e-7 on outputs -- removes a ~25-instr range-reduction from the
//     pre-barrier chain and its VGPR pressure.
//   - masked t==T-1 sets e=0 directly (softmax of -1e9 is exactly 0 in the
//     f32 reference too) -- no exp on that lane.
//   - atomics scatter UNSCALED e[k]; the 1/S divide overlaps the scatter and
//     the normalization folds into the final float4 store (4 mults).

constexpr int T = 2048;
constexpr int V = 8192;
constexpr int BLOCK = 256;
constexpr int PER = T / BLOCK;        // 8 positions per thread (contiguous)
constexpr int NWAVE = BLOCK / 64;     // 4 waves
constexpr int NCHUNK = 8;             // V-chunks per batch
constexpr int CHUNK = V / NCHUNK;     // 1024 floats = 4 KB

__global__ __launch_bounds__(BLOCK)
void ca_kernel(const int* __restrict__ x, const float* __restrict__ params,
               float* __restrict__ out) {
    const int b   = blockIdx.x >> 3;            // batch
    const int c   = blockIdx.x & (NCHUNK - 1);  // vocab chunk
    const int tid = threadIdx.x;

    __shared__ float s_acc[CHUNK];              // 4 KB chunk accumulator
    __shared__ float s_red[NWAVE];

    // zero the chunk: exactly one float4 per thread
    reinterpret_cast<float4*>(s_acc)[tid] = make_float4(0.f, 0.f, 0.f, 0.f);

    const int* xb = x + b * T;

    // wave-uniform query tokens (compiler scalarizes these)
    const int q0 = xb[T - 1], q1 = xb[T - 2], q2 = xb[T - 3];

    // params[i][j]: i = query index (x[T-1-i]), j = window offset (x[t-j])
    const float p00 = params[0], p01 = params[1], p02 = params[2];
    const float p10 = params[3], p11 = params[4], p12 = params[5];
    const float p20 = params[6], p21 = params[7], p22 = params[8];

    // per-thread contiguous window x[t0-2 .. t0+7]; sentinel -1 never matches
    const int t0 = tid * PER;
    int tok[PER];
    int m2, m1;
    {
        const int4 a = *reinterpret_cast<const int4*>(xb + t0);       // 16B-aligned
        const int4 d = *reinterpret_cast<const int4*>(xb + t0 + 4);
        tok[0] = a.x; tok[1] = a.y; tok[2] = a.z; tok[3] = a.w;
        tok[4] = d.x; tok[5] = d.y; tok[6] = d.z; tok[7] = d.w;
        if (tid > 0) {
            const int2 p = *reinterpret_cast<const int2*>(xb + t0 - 2); // 8B-aligned
            m2 = p.x; m1 = p.y;
        } else {
            m2 = -1; m1 = -1;   // t<j terms contribute 0 (zero-padding in ref)
        }
    }

    // --- scores + exp (no max-shift: |s| <= 9*max|param| << 80) ---
    float e[PER];
    float lsum = 0.f;
    #pragma unroll
    for (int k = 0; k < PER; ++k) {
        const int tj0 = tok[k];                                     // j = 0
        const int tj1 = (k >= 1) ? tok[k - 1] : m1;                 // j = 1
        const int tj2 = (k >= 2) ? tok[k - 2] : (k == 1 ? m1 : m2); // j = 2
        float s = 0.f;
        if (tj0 == q0) s += p00;
        if (tj0 == q1) s += p10;
        if (tj0 == q2) s += p20;
        if (tj1 == q0) s += p01;
        if (tj1 == q1) s += p11;
        if (tj1 == q2) s += p21;
        if (tj2 == q0) s += p02;
        if (tj2 == q1) s += p12;
        if (tj2 == q2) s += p22;
        // masked slot: softmax value is exactly 0 (exp(-1e9-max) underflows)
        e[k] = (t0 + k == T - 1) ? 0.f : __expf(s);
        lsum += e[k];
    }

    // --- block sum (one barrier covers both s_red and the s_acc zeroing) ---
    #pragma unroll
    for (int off = 32; off >= 1; off >>= 1)
        lsum += __shfl_down(lsum, off, 64);
    const int wave = tid >> 6, lane = tid & 63;
    if (lane == 0) s_red[wave] = lsum;
    __syncthreads();                                     // barrier 1

    // --- scatter UNSCALED attn weights into the chunk (ds_add_f32) ---
    // (the 1/S divide below overlaps this scatter; dup tokens rare)
    const int vbase = c * CHUNK;
    #pragma unroll
    for (int k = 0; k < PER; ++k) {
        const int v = tok[k] - vbase;
        if ((unsigned)v < (unsigned)CHUNK)
            atomicAdd(&s_acc[v], e[k]);
    }

    float S = 0.f;
    #pragma unroll
    for (int w = 0; w < NWAVE; ++w) S += s_red[w];
    const float inv = 1.f / S;

    __syncthreads();                                     // barrier 2

    // --- coalesced chunk store with normalization folded in ---
    float4 r = reinterpret_cast<const float4*>(s_acc)[tid];
    r.x *= inv; r.y *= inv; r.z *= inv; r.w *= inv;
    reinterpret_cast<float4*>(out + b * V + c * CHUNK)[tid] = r;
}

extern "C" void kernel_launch(void* const* d_in, const int* in_sizes, int n_in,
                              void* d_out, int out_size, void* d_ws, size_t ws_size,
                              hipStream_t stream) {
    const int* x = (const int*)d_in[0];          // (B, T) int32
    const float* params = (const float*)d_in[1]; // (3, 3) fp32
    float* out = (float*)d_out;                  // (B, V) fp32
    const int B = in_sizes[0] / T;               // 8
    ca_kernel<<<B * NCHUNK, BLOCK, 0, stream>>>(x, params, out);
}